// Round 1
// baseline (57.406 us; speedup 1.0000x reference)
//
#include <hip/hip_runtime.h>
#include <hip/hip_bf16.h>

// Problem: B=2048, IN=4096, OUT=4096, C=32
// out[b][o] = dot( {min,max,prod,coprod}_c x[b, conn[o][c]], softmax(w[o,:4]) )
//
// Strategy:
//   grid = B/B_TILE blocks; each block stages B_TILE=4 rows of x into LDS
//   (64 KB, XOR-swizzled per row so the 4 lanes sharing an index hit 4
//   spread banks), then computes all OUT=4096 outputs for those rows.
//   Lane layout per wave: 16 o-groups x 4 b-rows. Each thread owns one
//   b-row and 32 o's (stride 128).

#define B_TILE 4
#define THREADS 512
#define IN_DIM 4096
#define OUT_DIM 4096
#define CONN 32

__global__ __launch_bounds__(THREADS, 4) void ddlg_kernel(
    const float* __restrict__ x,
    const float* __restrict__ w,
    const int* __restrict__ conn,
    float* __restrict__ out) {
  __shared__ float xs[B_TILE * IN_DIM];  // exactly 64 KB

  const int b0 = blockIdx.x * B_TILE;

  // ---- Stage B_TILE rows of x into LDS with per-row XOR swizzle ----
  // float index within row i is stored at (i ^ (row*8)); xor flips bits 3-4
  // only, so a float4 (i aligned to 4) stays contiguous and 16B-aligned.
  {
    const float4* xf4 = (const float4*)(x + (size_t)b0 * IN_DIM);
    for (int t = threadIdx.x; t < B_TILE * (IN_DIM / 4); t += THREADS) {
      const int r = t >> 10;        // row 0..3
      const int i4 = t & 1023;      // float4 index within row
      float4 v = xf4[t];
      const int dst = (r << 12) + (((i4 << 2)) ^ (r << 3));
      *(float4*)(&xs[dst]) = v;
    }
  }
  __syncthreads();

  const int lane = threadIdx.x & 63;
  const int wave = threadIdx.x >> 6;
  const int bg = lane & 3;       // which of the 4 staged rows
  const int og = lane >> 2;      // 0..15
  const int o_slot = wave * 16 + og;  // 0..127
  const int rowbase = bg << 12;       // bg * 4096
  const int swz = bg << 3;            // bg * 8

  const int brow = b0 + bg;
  float* outrow = out + (size_t)brow * OUT_DIM;

#pragma unroll 1
  for (int r = 0; r < OUT_DIM / 128; ++r) {   // 32 o's per thread
    const int o = o_slot + (r << 7);

    // load 32 indices for this o (4 bg-lanes duplicate -> L1 merge)
    const int4* cp = (const int4*)(conn + o * CONN);
    int4 iv[8];
#pragma unroll
    for (int q = 0; q < 8; ++q) iv[q] = cp[q];

    float mn = 3.0e38f, mx = -3.0e38f, pr = 1.0f, co = 1.0f;
#pragma unroll
    for (int q = 0; q < 8; ++q) {
      int i0 = iv[q].x, i1 = iv[q].y, i2 = iv[q].z, i3 = iv[q].w;
      float f0 = xs[rowbase + (i0 ^ swz)];
      float f1 = xs[rowbase + (i1 ^ swz)];
      float f2 = xs[rowbase + (i2 ^ swz)];
      float f3 = xs[rowbase + (i3 ^ swz)];
      mn = fminf(mn, f0); mx = fmaxf(mx, f0); pr *= f0; co = __builtin_fmaf(-f0, co, co);
      mn = fminf(mn, f1); mx = fmaxf(mx, f1); pr *= f1; co = __builtin_fmaf(-f1, co, co);
      mn = fminf(mn, f2); mx = fmaxf(mx, f2); pr *= f2; co = __builtin_fmaf(-f2, co, co);
      mn = fminf(mn, f3); mx = fmaxf(mx, f3); pr *= f3; co = __builtin_fmaf(-f3, co, co);
    }

    // softmax(w[o, 0..3]) and dot
    const float4 wv = ((const float4*)w)[o];
    float m01 = fmaxf(wv.x, wv.y);
    float m23 = fmaxf(wv.z, wv.w);
    float m = fmaxf(m01, m23);
    float e0 = __expf(wv.x - m);
    float e1 = __expf(wv.y - m);
    float e2 = __expf(wv.z - m);
    float e3 = __expf(wv.w - m);
    float inv = 1.0f / (e0 + e1 + e2 + e3);
    float res = (mn * e0 + mx * e1 + pr * e2 + (1.0f - co) * e3) * inv;

    outrow[o] = res;
  }
}

extern "C" void kernel_launch(void* const* d_in, const int* in_sizes, int n_in,
                              void* d_out, int out_size, void* d_ws, size_t ws_size,
                              hipStream_t stream) {
  const float* x = (const float*)d_in[0];
  const float* w = (const float*)d_in[1];
  const int* conn = (const int*)d_in[2];
  float* out = (float*)d_out;

  const int B = 2048;
  dim3 grid(B / B_TILE);
  dim3 block(THREADS);
  ddlg_kernel<<<grid, block, 0, stream>>>(x, w, conn, out);
}